// Round 3
// baseline (240.597 us; speedup 1.0000x reference)
//
#include <hip/hip_runtime.h>
#include <hip/hip_bf16.h>

// Attention_4363686773373: sigmoid attention block, all-bf16 MFMA pipeline.
// B=4 T=2048 D=768 H=12 HD=64.  Output fp32.
// R14: attn rebuilt on 32x32x16 MFMA (2x FLOPs per LDS operand byte):
//  - 4 waves x 32 q-rows (256 thr), swapped QK^T (C = K.Q^T) so each lane
//    holds its own q-row's S in regs -> sigmoid + pack in-register, P never
//    touches LDS (k-pos permutation s-bits 2<->3 baked into vT).
//  - Q loaded global->reg directly (no LDS staging). LDS = K/V dbuf = 32KB.
//  - per-tile LDS reads: 16 b128/wave (was 18) at HALF the wave count.
// GEMMs: distance-2 named-register prefetch, launch_bounds(256,2) (R10).

typedef __bf16 bf16_t;
typedef __bf16 bf16x8 __attribute__((ext_vector_type(8)));
typedef __bf16 bf16x4 __attribute__((ext_vector_type(4)));
typedef __bf16 bf16x2 __attribute__((ext_vector_type(2)));
typedef float floatx4 __attribute__((ext_vector_type(4)));
typedef float floatx16 __attribute__((ext_vector_type(16)));

#define MFMA16x16x32(a, b, c) __builtin_amdgcn_mfma_f32_16x16x32_bf16((a), (b), (c), 0, 0, 0)
#define MFMA32x32x16(a, b, c) __builtin_amdgcn_mfma_f32_32x32x16_bf16((a), (b), (c), 0, 0, 0)

static constexpr float kEPS  = 1e-4f;
static constexpr float kGAIN = 1.8402f;
static constexpr float kC    = -0.18033688011112042f;   // -0.125 * log2(e)

#if __has_builtin(__builtin_amdgcn_cvt_pk_bf16_f32)
__device__ __forceinline__ bf16x2 pk_bf16(float a, float b) {
    return __builtin_amdgcn_cvt_pk_bf16_f32(a, b);
}
#else
__device__ __forceinline__ bf16x2 pk_bf16(float a, float b) {
    bf16x2 r; r[0] = (bf16_t)a; r[1] = (bf16_t)b; return r;
}
#endif

__device__ __forceinline__ float sigm(float x) {
    return __builtin_amdgcn_rcpf(1.0f + __builtin_amdgcn_exp2f(x));
}

// sigmoid 8 fp32 -> packed bf16x8 (A-fragment for PV)
__device__ __forceinline__ bf16x8 sig_pack8(float a0, float a1, float a2, float a3,
                                            float a4, float a5, float a6, float a7) {
    bf16x2 q0 = pk_bf16(sigm(a0), sigm(a1));
    bf16x2 q1 = pk_bf16(sigm(a2), sigm(a3));
    bf16x2 q2 = pk_bf16(sigm(a4), sigm(a5));
    bf16x2 q3 = pk_bf16(sigm(a6), sigm(a7));
    bf16x4 lo = __builtin_shufflevector(q0, q1, 0, 1, 2, 3);
    bf16x4 hi = __builtin_shufflevector(q2, q3, 0, 1, 2, 3);
    return __builtin_shufflevector(lo, hi, 0, 1, 2, 3, 4, 5, 6, 7);
}

// ---------------------------------------------------------------------------
// 1) merged preprocessing:
//    blocks [0,3072): row-normalize [qkv_w ; out_w] rows -> bf16
//    blocks [3072,11264): x -> bf16 + per-token magnitude ||x||/sqrt(D)
// ---------------------------------------------------------------------------
__global__ __launch_bounds__(256) void prep_kernel(const float* __restrict__ x,
                                                   const float* __restrict__ qkv_w,
                                                   const float* __restrict__ out_w,
                                                   bf16_t* __restrict__ wn_all,
                                                   bf16_t* __restrict__ xb,
                                                   float* __restrict__ mag) {
    __shared__ float red[4];
    int b = blockIdx.x;
    if (b < 3072) {
        const float* wr = (b < 2304) ? qkv_w + (size_t)b * 768
                                     : out_w + (size_t)(b - 2304) * 768;
        float ss = 0.f;
        for (int c = threadIdx.x; c < 768; c += 256) { float v = wr[c]; ss += v * v; }
        for (int m = 32; m; m >>= 1) ss += __shfl_xor(ss, m, 64);
        if ((threadIdx.x & 63) == 0) red[threadIdx.x >> 6] = ss;
        __syncthreads();
        float inv = 1.0f / (sqrtf(red[0] + red[1] + red[2] + red[3]) + kEPS);
        bf16_t* wo = wn_all + (size_t)b * 768;
        for (int c = threadIdx.x; c < 768; c += 256) wo[c] = (bf16_t)(wr[c] * inv);
    } else {
        int tok = b - 3072;               // 0..8191
        const float* xr = x + (size_t)tok * 768;
        float ss = 0.f;
        for (int c = threadIdx.x; c < 768; c += 256) { float v = xr[c]; ss += v * v; }
        for (int m = 32; m; m >>= 1) ss += __shfl_xor(ss, m, 64);
        if ((threadIdx.x & 63) == 0) red[threadIdx.x >> 6] = ss;
        __syncthreads();
        float tot = red[0] + red[1] + red[2] + red[3];
        if (threadIdx.x == 0) mag[tok] = sqrtf(tot) * 0.036084391824352f;  // 1/sqrt(768)
        bf16_t* xo = xb + (size_t)tok * 768;
        for (int c = threadIdx.x; c < 768; c += 256) xo[c] = (bf16_t)xr[c];
    }
}

// ---------------------------------------------------------------------------
// 3) GEMM1: qkv = xb(8192x768) @ wn^T(2304x768).  128x128 tile, BK=32,
//    distance-2 register prefetch with NAMED registers. Lane-order LDS.
//    Epilogue: q/k per-head normalize (q also *kC) -> qkvh; v (p==2)
//    transposed via LDS to vT.  R14: vT column permutation = swap of s-bits
//    2<->3 within each 64-tile (matches attn's in-register P k-ordering).
// ---------------------------------------------------------------------------
__global__ __launch_bounds__(256, 2) void gemm_qkv_kernel(const bf16_t* __restrict__ A,
                                                          const bf16_t* __restrict__ Bw,
                                                          bf16_t* __restrict__ qkvh,
                                                          bf16_t* __restrict__ vT) {
    __shared__ __align__(16) bf16_t sm[8704];   // As 4096 | Bs 4096; reused 64x136 for v-transpose
    bf16_t* As = sm;
    bf16_t* Bs = sm + 4096;

    const int m0 = blockIdx.x * 128;
    const int n0 = blockIdx.y * 128;
    const int tid = threadIdx.x;
    const int wave = tid >> 6, lane = tid & 63;
    const int quad = lane >> 4, l16 = lane & 15;
    const int wr = (wave >> 1) * 64, wc = (wave & 1) * 64;
    const int srow = lane & 15, schunk = lane >> 4;   // staging lane map

    floatx4 acc[4][4];
    for (int i = 0; i < 4; i++)
        for (int j = 0; j < 4; j++) acc[i][j] = (floatx4){0.f, 0.f, 0.f, 0.f};

    const bf16_t* aptr0 = A  + (size_t)(m0 + wave * 32 + srow) * 768 + schunk * 8;
    const bf16_t* bptr0 = Bw + (size_t)(n0 + wave * 32 + srow) * 768 + schunk * 8;
    const int abase = wave * 1024;                    // per-wave region: 2 x 512

    // two prefetch sets, NAMED registers (arrays spilled in R9)
    uint4 aA0, aA1, bA0, bA1, aB0, aB1, bB0, bB1;

    aA0 = *(const uint4*)(aptr0 + 0);
    aA1 = *(const uint4*)(aptr0 + 0 + 16 * 768);
    bA0 = *(const uint4*)(bptr0 + 0);
    bA1 = *(const uint4*)(bptr0 + 0 + 16 * 768);
    aB0 = *(const uint4*)(aptr0 + 32);
    aB1 = *(const uint4*)(aptr0 + 32 + 16 * 768);
    bB0 = *(const uint4*)(bptr0 + 32);
    bB1 = *(const uint4*)(bptr0 + 32 + 16 * 768);

    auto compute = [&]() {
        bf16x8 af[4], bfr[4];
#pragma unroll
        for (int i = 0; i < 4; i++)
            af[i] = *(const bf16x8*)&As[((wr >> 4) + i) * 512 + quad * 128 + l16 * 8];
#pragma unroll
        for (int j = 0; j < 4; j++)
            bfr[j] = *(const bf16x8*)&Bs[((wc >> 4) + j) * 512 + quad * 128 + l16 * 8];
#pragma unroll
        for (int i = 0; i < 4; i++)
#pragma unroll
            for (int j = 0; j < 4; j++) acc[i][j] = MFMA16x16x32(af[i], bfr[j], acc[i][j]);
    };

    for (int u = 0; u < 12; ++u) {
        // even iteration: consume set A, refill A for k=(2u+2)*32
        __syncthreads();
        *(uint4*)&As[abase + lane * 8]       = aA0;
        *(uint4*)&As[abase + 512 + lane * 8] = aA1;
        *(uint4*)&Bs[abase + lane * 8]       = bA0;
        *(uint4*)&Bs[abase + 512 + lane * 8] = bA1;
        if (u < 11) {
            int k0 = (2 * u + 2) * 32;
            aA0 = *(const uint4*)(aptr0 + k0);
            aA1 = *(const uint4*)(aptr0 + k0 + 16 * 768);
            bA0 = *(const uint4*)(bptr0 + k0);
            bA1 = *(const uint4*)(bptr0 + k0 + 16 * 768);
        }
        __syncthreads();
        compute();

        // odd iteration: consume set B, refill B for k=(2u+3)*32
        __syncthreads();
        *(uint4*)&As[abase + lane * 8]       = aB0;
        *(uint4*)&As[abase + 512 + lane * 8] = aB1;
        *(uint4*)&Bs[abase + lane * 8]       = bB0;
        *(uint4*)&Bs[abase + 512 + lane * 8] = bB1;
        if (u < 11) {
            int k0 = (2 * u + 3) * 32;
            aB0 = *(const uint4*)(aptr0 + k0);
            aB1 = *(const uint4*)(aptr0 + k0 + 16 * 768);
            bB0 = *(const uint4*)(bptr0 + k0);
            bB1 = *(const uint4*)(bptr0 + k0 + 16 * 768);
        }
        __syncthreads();
        compute();
    }

    const int p = n0 / 768;        // block-uniform (768 % 128 == 0)
    const int bat = m0 >> 11, t0 = m0 & 2047;

    if (p < 2) {
        // ---- q/k: fused per-head normalize, scatter to qkvh ----
        const int h = ((n0 + wc) - p * 768) >> 6;
        const float base = (p == 0) ? kC * 8.0f : 8.0f;
        for (int i = 0; i < 4; i++)
            for (int r = 0; r < 4; r++) {
                float vals[4], ss = 0.f;
                for (int j = 0; j < 4; j++) { float v = acc[i][j][r]; vals[j] = v; ss += v * v; }
                ss += __shfl_xor(ss, 1, 64);
                ss += __shfl_xor(ss, 2, 64);
                ss += __shfl_xor(ss, 4, 64);
                ss += __shfl_xor(ss, 8, 64);
                float scale = base / (sqrtf(ss) + kEPS);
                int m = m0 + wr + i * 16 + quad * 4 + r;
                int t = m & 2047;
                bf16_t* dst = qkvh + ((((size_t)p * 4 + bat) * 12 + h) * 2048 + t) * 64;
                for (int j = 0; j < 4; j++) dst[j * 16 + l16] = (bf16_t)(vals[j] * scale);
            }
    } else {
        // ---- v: transpose via LDS, write vT[(bh)*64+d][t] (bit-2/3-swapped cols) ----
        __syncthreads();                         // everyone done with As/Bs
        const int h0 = (n0 - 1536) >> 6;         // block head base (2 heads/block)
        for (int hh = 0; hh < 2; hh++) {
            if ((wc >> 6) == hh) {
                for (int i = 0; i < 4; i++)
                    for (int r = 0; r < 4; r++) {
                        int tl = wr + i * 16 + quad * 4 + r;
                        for (int j = 0; j < 4; j++)
                            sm[(j * 16 + l16) * 136 + tl] = (bf16_t)acc[i][j][r];
                    }
            }
            __syncthreads();
            bf16_t* dst = vT + ((size_t)(bat * 12 + h0 + hh) * 64) * 2048 + t0;
            for (int u = tid; u < 1024; u += 256) {
                int d = u >> 4, c = u & 15;
                bf16_t tmp[8];
#pragma unroll
                for (int q = 0; q < 8; q++) {
                    int sp = c * 8 + q;                      // out position 0..127
                    int q6 = sp & 63;
                    // pos->s within 64-tile: swap bits 2 and 3 (involution)
                    int tl = (sp & 64) + ((q6 & 51) | ((q6 & 4) << 1) | ((q6 & 8) >> 1));
                    tmp[q] = sm[d * 136 + tl];
                }
                *(uint4*)&dst[(size_t)d * 2048 + c * 8] = *(uint4*)tmp;
            }
            __syncthreads();
        }
    }
}

// ---------------------------------------------------------------------------
// 6) sigmoid attention, fused per-head output normalize + mag rescale.
//    grid (48, 16): x = head (XCD-affine), y = q-tile of 128 rows.
//    256 thr = 4 waves x 32 q-rows.  32x32x16 MFMA throughout.
//    Swapped QK^T: C[mb] = K[mb-rows].Q^T -> lane (l32,hl) holds
//    S[q=l32][s = (r&3)+8*(r>>2)+4*hl + 32*mb] in C-reg r.  Sigmoid+pack
//    in-register; contiguous C-reg octets ARE the PV A-fragments under the
//    pos->s bit-2/3-swap permutation (baked into vT, so PV's k-dim is
//    consistent).  P never touches LDS.  LDS: K/V double-buffer = 32 KB.
// ---------------------------------------------------------------------------
__global__ __launch_bounds__(256, 3) void attn_kernel(const bf16_t* __restrict__ qkvh,
                                                      const bf16_t* __restrict__ vT,
                                                      const float* __restrict__ mag,
                                                      bf16_t* __restrict__ y) {
    __shared__ bf16_t Ksh[2][64 * 64];
    __shared__ bf16_t Vsh[2][64 * 64];       // [d][pos] (pos = bit-2/3-swapped s)

    const int bh = blockIdx.x, bat = bh / 12, head = bh % 12;
    const int m0 = blockIdx.y * 128;
    const bf16_t* qbase = qkvh + (((size_t)bat * 12 + head) * 2048) * 64;         // p=0
    const bf16_t* kbase = qkvh + (((size_t)(4 + bat) * 12 + head) * 2048) * 64;   // p=1
    const bf16_t* vbase = vT + ((size_t)bh * 64) * 2048;

    const int tid = threadIdx.x, wave = tid >> 6, lane = tid & 63;
    const int l32 = lane & 31, hl = lane >> 5;

    // ---- K/V staging: 2 uint4 of each per thread ----
    const int slr = tid >> 3, slb = tid & 7;         // slr 0..31, slb 0..7
    const int sw = ((slb ^ (slr & 7)) * 8);          // (32+slr)&7 == slr&7
    uint4 kr0, kr1, vr0, vr1;
    auto issue = [&](int s0) {
        kr0 = *(const uint4*)&kbase[(size_t)(s0 + slr) * 64 + slb * 8];
        kr1 = *(const uint4*)&kbase[(size_t)(s0 + 32 + slr) * 64 + slb * 8];
        vr0 = *(const uint4*)&vbase[(size_t)slr * 2048 + s0 + slb * 8];
        vr1 = *(const uint4*)&vbase[(size_t)(32 + slr) * 2048 + s0 + slb * 8];
    };
    auto commit = [&](int buf) {
        *(uint4*)&Ksh[buf][slr * 64 + sw]        = kr0;
        *(uint4*)&Ksh[buf][(32 + slr) * 64 + sw] = kr1;
        *(uint4*)&Vsh[buf][slr * 64 + sw]        = vr0;
        *(uint4*)&Vsh[buf][(32 + slr) * 64 + sw] = vr1;
    };

    issue(0);

    // ---- Q fragments: direct global->reg (B-operand: col=own q-row l32,
    //      k-elems d = 16t + 8*hl + j) ----
    const int qrow = m0 + wave * 32 + l32;
    const bf16_t* qp = qbase + (size_t)qrow * 64 + hl * 8;
    bf16x8 qf0 = *(const bf16x8*)(qp + 0);
    bf16x8 qf1 = *(const bf16x8*)(qp + 16);
    bf16x8 qf2 = *(const bf16x8*)(qp + 32);
    bf16x8 qf3 = *(const bf16x8*)(qp + 48);

    commit(0);
    issue(64);
    __syncthreads();   // Ksh[0]/Vsh[0] visible

    // hoisted LDS read offsets (rows mb*32+l32 share l32&7)
    const int rx = l32 & 7;
    const int ra = l32 * 64, rb = (32 + l32) * 64;
    const int c0a = ((0 + hl) ^ rx) * 8;
    const int c1a = ((2 + hl) ^ rx) * 8;
    const int c2a = ((4 + hl) ^ rx) * 8;
    const int c3a = ((6 + hl) ^ rx) * 8;

    const floatx16 fz16 = {0.f, 0.f, 0.f, 0.f, 0.f, 0.f, 0.f, 0.f,
                           0.f, 0.f, 0.f, 0.f, 0.f, 0.f, 0.f, 0.f};
    floatx16 o0 = fz16, o1 = fz16;

    for (int it = 0; it < 32; ++it) {
        const bf16_t* Ks = Ksh[it & 1];
        const bf16_t* Vt = Vsh[it & 1];
        if (it < 31) {
            commit((it + 1) & 1);            // regs from issue one iter ago
            if (it < 30) issue((it + 2) * 64);
        }

        // ---- S^T = K.Q^T : c0 = s-rows 0..31, c1 = s-rows 32..63 ----
        floatx16 s0v, s1v;
        {
            bf16x8 ka = *(const bf16x8*)&Ks[ra + c0a];
            bf16x8 kb = *(const bf16x8*)&Ks[rb + c0a];
            s0v = MFMA32x32x16(ka, qf0, fz16);
            s1v = MFMA32x32x16(kb, qf0, fz16);
        }
        {
            bf16x8 ka = *(const bf16x8*)&Ks[ra + c1a];
            bf16x8 kb = *(const bf16x8*)&Ks[rb + c1a];
            s0v = MFMA32x32x16(ka, qf1, s0v);
            s1v = MFMA32x32x16(kb, qf1, s1v);
        }
        {
            bf16x8 ka = *(const bf16x8*)&Ks[ra + c2a];
            bf16x8 kb = *(const bf16x8*)&Ks[rb + c2a];
            s0v = MFMA32x32x16(ka, qf2, s0v);
            s1v = MFMA32x32x16(kb, qf2, s1v);
        }
        {
            bf16x8 ka = *(const bf16x8*)&Ks[ra + c3a];
            bf16x8 kb = *(const bf16x8*)&Ks[rb + c3a];
            s0v = MFMA32x32x16(ka, qf3, s0v);
            s1v = MFMA32x32x16(kb, qf3, s1v);
        }

        // ---- sigmoid in-register; contiguous reg octets = PV A-frags ----
        bf16x8 p0 = sig_pack8(s0v[0], s0v[1], s0v[2],  s0v[3],  s0v[4],  s0v[5],  s0v[6],  s0v[7]);
        bf16x8 p1 = sig_pack8(s0v[8], s0v[9], s0v[10], s0v[11], s0v[12], s0v[13], s0v[14], s0v[15]);
        bf16x8 p2 = sig_pack8(s1v[0], s1v[1], s1v[2],  s1v[3],  s1v[4],  s1v[5],  s1v[6],  s1v[7]);
        bf16x8 p3 = sig_pack8(s1v[8], s1v[9], s1v[10], s1v[11], s1v[12], s1v[13], s1v[14], s1v[15]);

        // ---- O += P.V  (B-frags from Vsh[d][pos], same chunk offsets) ----
        {
            bf16x8 va = *(const bf16x8*)&Vt[ra + c0a];
            bf16x8 vb = *(const bf16x8*)&Vt[rb + c0a];
            o0 = MFMA32x32x16(p0, va, o0);
            o1 = MFMA32x32x16(p0, vb, o1);
        }
        {
            bf16x8 va = *(const bf16x8*)&Vt[ra + c1a];
            bf16x8 vb = *(const bf16x8*)&Vt[rb + c1a];
            o0 = MFMA32x32x16(p1, va, o0);
            o1 = MFMA32x32x16(p1, vb, o1);
        }
        {
            bf16x8 va = *(const bf16x8*)&Vt[ra + c2a];
            bf16x8 vb = *(const bf16x8*)&Vt[rb + c2a];
            o0 = MFMA32x32x16(p2, va, o0);
            o1 = MFMA32x32x16(p2, vb, o1);
        }
        {
            bf16x8 va = *(const bf16x8*)&Vt[ra + c3a];
            bf16x8 vb = *(const bf16x8*)&Vt[rb + c3a];
            o0 = MFMA32x32x16(p3, va, o0);
            o1 = MFMA32x32x16(p3, vb, o1);
        }
        __syncthreads();   // one barrier per s-tile
    }

    // ---- epilogue: out = mag * 8 * (kGAIN/sqrt(T)) * o / (||o'|| + eps) ----
    // O layout: col d = nb*32 + l32, row q = (r&3) + 8*(r>>2) + 4*hl
    const float kfac = kGAIN * 0.02209708691207961f;  // 1.8402/sqrt(2048)
    const float* magb = mag + bat * 2048 + m0 + wave * 32;
    bf16_t* yb = y + ((size_t)(bat * 2048 + m0 + wave * 32)) * 768 + head * 64;
#pragma unroll
    for (int r = 0; r < 16; r++) {
        int qr = (r & 3) + 8 * (r >> 2) + 4 * hl;
        float v0 = o0[r] * kfac, v1 = o1[r] * kfac;
        float ss = v0 * v0 + v1 * v1;
        ss += __shfl_xor(ss, 1, 64);
        ss += __shfl_xor(ss, 2, 64);
        ss += __shfl_xor(ss, 4, 64);
        ss += __shfl_xor(ss, 8, 64);
        ss += __shfl_xor(ss, 16, 64);          // masks <32: halves stay separate
        float sc = magb[qr] * 8.0f / (sqrtf(ss) + kEPS);
        bf16_t* yp = yb + (size_t)qr * 768;
        yp[l32]      = (bf16_t)(v0 * sc);
        yp[32 + l32] = (bf16_t)(v1 * sc);
    }
}

// ---------------------------------------------------------------------------
// 7) GEMM2: out = y(8192x768) @ ow^T(768x768) -> fp32, BK=32, distance-2
//    (named prefetch registers, launch_bounds(256,2))
// ---------------------------------------------------------------------------
__global__ __launch_bounds__(256, 2) void gemm_out_kernel(const bf16_t* __restrict__ A,
                                                          const bf16_t* __restrict__ Bw,
                                                          float* __restrict__ out) {
    __shared__ __align__(16) bf16_t sm[8192];
    bf16_t* As = sm;
    bf16_t* Bs = sm + 4096;

    const int m0 = blockIdx.x * 128;
    const int n0 = blockIdx.y * 128;
    const int tid = threadIdx.x;
    const int wave = tid >> 6, lane = tid & 63;
    const int quad = lane >> 4, l16 = lane & 15;
    const int wr = (wave >> 1) * 64, wc = (wave & 1) * 64;
    const int srow = lane & 15, schunk = lane >> 4;

    floatx4 acc[4][4];
    for (int i = 0; i < 4; i++)
        for (int j = 0; j < 4; j++) acc[i][j] = (floatx4){0.f, 0.f, 0.f, 0.f};

    const bf16_t* aptr0 = A  + (size_t)(m0 + wave * 32 + srow) * 768 + schunk * 8;
    const bf16_t* bptr0 = Bw + (size_t)(n0 + wave * 32 + srow) * 768 + schunk * 8;
    const int abase = wave * 1024;

    uint4 aA0, aA1, bA0, bA1, aB0, aB1, bB0, bB1;

    aA0 = *(const uint4*)(aptr0 + 0);
    aA1 = *(const uint4*)(aptr0 + 0 + 16 * 768);
    bA0 = *(const uint4*)(bptr0 + 0);
    bA1 = *(const uint4*)(bptr0 + 0 + 16 * 768);
    aB0 = *(const uint4*)(aptr0 + 32);
    aB1 = *(const uint4*)(aptr0 + 32 + 16 * 768);
    bB0 = *(const uint4*)(bptr0 + 32);
    bB1 = *(const uint4*)(bptr0 + 32 + 16 * 768);

    auto compute = [&]() {
        bf16x8 af[4], bfr[4];
#pragma unroll
        for (int i = 0; i < 4; i++)
            af[i] = *(const bf16x8*)&As[((wr >> 4) + i) * 512 + quad * 128 + l16 * 8];
#pragma unroll
        for (int j = 0; j < 4; j++)
            bfr[j] = *(const bf16x8*)&Bs[((wc >> 4) + j) * 512 + quad * 128 + l16 * 8];
#pragma unroll
        for (int i = 0; i < 4; i++)
#pragma unroll
            for (int j = 0; j < 4; j++) acc[i][j] = MFMA16x16x32(af[i], bfr[j], acc[i][j]);
    };

    for (int u = 0; u < 12; ++u) {
        __syncthreads();
        *(uint4*)&As[abase + lane * 8]       = aA0;
        *(uint4*)&As[abase + 512 + lane * 8] = aA1;
        *(uint4*)&Bs[abase + lane * 8]       = bA0;
        *(uint4*)&Bs[abase + 512 + lane * 8] = bA1;
        if (u < 11) {
            int k0 = (2 * u + 2) * 32;
            aA0 = *(const uint4*)(aptr0 + k0);
            aA1 = *(const uint4*)(aptr0 + k0 + 16 * 768);
            bA0 = *(const uint4*)(bptr0 + k0);
            bA1 = *(const uint4*)(bptr0 + k0 + 16 * 768);
        }
        __syncthreads();
        compute();

        __syncthreads();
        *(uint4*)&As[abase + lane * 8]       = aB0;
        *(uint4*)&As[abase + 512 + lane * 8] = aB1;
        *(uint4*)&Bs[abase + lane * 8]       = bB0;
        *(uint4*)&Bs[abase + 512 + lane * 8] = bB1;
        if (u < 11) {
            int k0 = (2 * u + 3) * 32;
            aB0 = *(const uint4*)(aptr0 + k0);
            aB1 = *(const uint4*)(aptr0 + k0 + 16 * 768);
            bB0 = *(const uint4*)(bptr0 + k0);
            bB1 = *(const uint4*)(bptr0 + k0 + 16 * 768);
        }
        __syncthreads();
        compute();
    }

    for (int i = 0; i < 4; i++)
        for (int j = 0; j < 4; j++) {
            int n = n0 + wc + j * 16 + l16;
            for (int r = 0; r < 4; r++) {
                int m = m0 + wr + i * 16 + quad * 4 + r;
                out[(size_t)m * 768 + n] = acc[i][j][r];
            }
        }
}

// ---------------------------------------------------------------------------
extern "C" void kernel_launch(void* const* d_in, const int* in_sizes, int n_in,
                              void* d_out, int out_size, void* d_ws, size_t ws_size,
                              hipStream_t stream) {
    const float* x     = (const float*)d_in[0];   // (4,2048,768)
    const float* qkv_w = (const float*)d_in[1];   // (2304,768)
    const float* out_w = (const float*)d_in[2];   // (768,768)
    float* out = (float*)d_out;

    char* ws = (char*)d_ws;
    bf16_t* wn_all = (bf16_t*)(ws + 0);          //  4,718,592  (3072x768 bf16: qkv_w rows then out_w rows)
    bf16_t* xb     = (bf16_t*)(ws + 4718592);    // 12,582,912  (8192x768 bf16)
    float*  mag    = (float*) (ws + 17301504);   //     32,768  (8192 fp32)
    bf16_t* qkvh   = (bf16_t*)(ws + 17334272);   // 25,165,824  (2x4x12x2048x64 bf16: q,k)
    bf16_t* vT     = (bf16_t*)(ws + 42500096);   // 12,582,912  (48x64x2048 bf16, bit-2/3-swapped cols)
    bf16_t* y      = (bf16_t*)(ws + 55083008);   // 12,582,912  (8192x768 bf16)
    // total 67,665,920 bytes

    bf16_t* ow = wn_all + (size_t)2304 * 768;

    prep_kernel<<<11264, 256, 0, stream>>>(x, qkv_w, out_w, wn_all, xb, mag);
    gemm_qkv_kernel<<<dim3(64, 18), 256, 0, stream>>>(xb, wn_all, qkvh, vT);
    attn_kernel<<<dim3(48, 16), 256, 0, stream>>>(qkvh, vT, mag, y);
    gemm_out_kernel<<<dim3(64, 6), 256, 0, stream>>>(y, ow, out);
}